// Round 1
// baseline (430.685 us; speedup 1.0000x reference)
//
#include <hip/hip_runtime.h>

#define Hh 1024
#define NHh 16
#define HDh 64
#define Bb 8
#define SS 1024
#define Mtot (Bb*SS)   // 8192

typedef unsigned short ushortT;
typedef __attribute__((ext_vector_type(8))) short short8;
typedef __attribute__((ext_vector_type(4))) float floatx4;

__device__ __forceinline__ ushortT f2bf(float x) {
    union { float f; unsigned int u; } cv; cv.f = x;
    unsigned int u = cv.u;
    unsigned int r = u + 0x7fffu + ((u >> 16) & 1u);
    return (ushortT)(r >> 16);
}

__device__ __forceinline__ void gload_lds16(const ushortT* g, ushortT* l) {
    __builtin_amdgcn_global_load_lds(
        (const __attribute__((address_space(1))) void*)g,
        (__attribute__((address_space(3))) void*)l, 16, 0, 0);
}

// ---------------- fp32 -> bf16 converters ----------------
__global__ __launch_bounds__(256) void cvt_x(const float* __restrict__ in,
                                             ushortT* __restrict__ out, int n4) {
    int i = blockIdx.x * 256 + threadIdx.x;
    if (i >= n4) return;
    float4 f = ((const float4*)in)[i];
    uint2 o;
    o.x = (unsigned)f2bf(f.x) | ((unsigned)f2bf(f.y) << 16);
    o.y = (unsigned)f2bf(f.z) | ((unsigned)f2bf(f.w) << 16);
    ((uint2*)out)[i] = o;
}

__global__ __launch_bounds__(256) void cvt_w(const float* __restrict__ W0, const float* __restrict__ W1,
                                             const float* __restrict__ W2, const float* __restrict__ W3,
                                             ushortT* __restrict__ o0, ushortT* __restrict__ o1,
                                             ushortT* __restrict__ o2, ushortT* __restrict__ o3, int n4) {
    int z = blockIdx.y;
    const float* in = (z == 0) ? W0 : (z == 1) ? W1 : (z == 2) ? W2 : W3;
    ushortT* out = (z == 0) ? o0 : (z == 1) ? o1 : (z == 2) ? o2 : o3;
    int i = blockIdx.x * 256 + threadIdx.x;
    if (i >= n4) return;
    float4 f = ((const float4*)in)[i];
    uint2 o;
    o.x = (unsigned)f2bf(f.x) | ((unsigned)f2bf(f.y) << 16);
    o.y = (unsigned)f2bf(f.z) | ((unsigned)f2bf(f.w) << 16);
    ((uint2*)out)[i] = o;
}

// ---------------- QKV GEMM: out[m,n] = sum_k X[m,k]*W[n,k] + b[n] ----------------
// 128x128 tile, BK=32, 256 threads (4 waves, each 64x64), m97 structure.
__global__ __launch_bounds__(256) void qkv_gemm(const ushortT* __restrict__ X,
        const ushortT* __restrict__ W0, const ushortT* __restrict__ W1, const ushortT* __restrict__ W2,
        const float* __restrict__ b0, const float* __restrict__ b1, const float* __restrict__ b2,
        ushortT* __restrict__ Qo, ushortT* __restrict__ Ko, ushortT* __restrict__ Vo) {
    __shared__ ushortT As[128 * 32];
    __shared__ ushortT Bs[128 * 32];
    const int tid = threadIdx.x;
    const int lane = tid & 63;
    const int w = tid >> 6;
    const int qd = lane >> 4;
    const int ln = lane & 15;
    const int z = blockIdx.z;
    const ushortT* Wt = (z == 0) ? W0 : (z == 1) ? W1 : W2;
    const float* bias = (z == 0) ? b0 : (z == 1) ? b1 : b2;
    ushortT* Out = (z == 0) ? Qo : (z == 1) ? Ko : Vo;
    const int m0 = blockIdx.y * 128;
    const int n0 = blockIdx.x * 128;
    const int RM = (w >> 1) * 64;
    const int RN = (w & 1) * 64;

    floatx4 acc[4][4];
#pragma unroll
    for (int i = 0; i < 4; i++)
#pragma unroll
        for (int j = 0; j < 4; j++) acc[i][j] = (floatx4){0.f, 0.f, 0.f, 0.f};

    const int c0 = tid, c1 = tid + 256;
    for (int k0 = 0; k0 < 1024; k0 += 32) {
        gload_lds16(X + (m0 + (c0 >> 2)) * 1024 + k0 + (c0 & 3) * 8, As + c0 * 8);
        gload_lds16(X + (m0 + (c1 >> 2)) * 1024 + k0 + (c1 & 3) * 8, As + c1 * 8);
        gload_lds16(Wt + (n0 + (c0 >> 2)) * 1024 + k0 + (c0 & 3) * 8, Bs + c0 * 8);
        gload_lds16(Wt + (n0 + (c1 >> 2)) * 1024 + k0 + (c1 & 3) * 8, Bs + c1 * 8);
        __syncthreads();
        short8 af[4], bf8[4];
#pragma unroll
        for (int i = 0; i < 4; i++) af[i] = *(const short8*)&As[(RM + i * 16 + ln) * 32 + qd * 8];
#pragma unroll
        for (int j = 0; j < 4; j++) bf8[j] = *(const short8*)&Bs[(RN + j * 16 + ln) * 32 + qd * 8];
#pragma unroll
        for (int i = 0; i < 4; i++)
#pragma unroll
            for (int j = 0; j < 4; j++)
                acc[i][j] = __builtin_amdgcn_mfma_f32_16x16x32_bf16(af[i], bf8[j], acc[i][j], 0, 0, 0);
        __syncthreads();
    }

#pragma unroll
    for (int j = 0; j < 4; j++) {
        int n = n0 + RN + j * 16 + ln;
        float bb = bias[n];
        int h = n >> 6, d = n & 63;
#pragma unroll
        for (int i = 0; i < 4; i++) {
#pragma unroll
            for (int r = 0; r < 4; r++) {
                int m = m0 + RM + i * 16 + qd * 4 + r;
                int b = m >> 10, s = m & 1023;
                float v = acc[i][j][r] + bb;
                Out[(size_t)((b * NHh + h) * 1024 + s) * 64 + d] = f2bf(v);
            }
        }
    }
}

// ---------------- out-proj GEMM: proj[m,n] = sum_k C[m,k]*Wo[n,k] + bo[n] (fp32 out) ----------------
__global__ __launch_bounds__(256) void oproj_gemm(const ushortT* __restrict__ A,
        const ushortT* __restrict__ Wt, const float* __restrict__ bias, float* __restrict__ Pj) {
    __shared__ ushortT As[128 * 32];
    __shared__ ushortT Bs[128 * 32];
    const int tid = threadIdx.x;
    const int lane = tid & 63;
    const int w = tid >> 6;
    const int qd = lane >> 4;
    const int ln = lane & 15;
    const int m0 = blockIdx.y * 128;
    const int n0 = blockIdx.x * 128;
    const int RM = (w >> 1) * 64;
    const int RN = (w & 1) * 64;

    floatx4 acc[4][4];
#pragma unroll
    for (int i = 0; i < 4; i++)
#pragma unroll
        for (int j = 0; j < 4; j++) acc[i][j] = (floatx4){0.f, 0.f, 0.f, 0.f};

    const int c0 = tid, c1 = tid + 256;
    for (int k0 = 0; k0 < 1024; k0 += 32) {
        gload_lds16(A + (m0 + (c0 >> 2)) * 1024 + k0 + (c0 & 3) * 8, As + c0 * 8);
        gload_lds16(A + (m0 + (c1 >> 2)) * 1024 + k0 + (c1 & 3) * 8, As + c1 * 8);
        gload_lds16(Wt + (n0 + (c0 >> 2)) * 1024 + k0 + (c0 & 3) * 8, Bs + c0 * 8);
        gload_lds16(Wt + (n0 + (c1 >> 2)) * 1024 + k0 + (c1 & 3) * 8, Bs + c1 * 8);
        __syncthreads();
        short8 af[4], bf8[4];
#pragma unroll
        for (int i = 0; i < 4; i++) af[i] = *(const short8*)&As[(RM + i * 16 + ln) * 32 + qd * 8];
#pragma unroll
        for (int j = 0; j < 4; j++) bf8[j] = *(const short8*)&Bs[(RN + j * 16 + ln) * 32 + qd * 8];
#pragma unroll
        for (int i = 0; i < 4; i++)
#pragma unroll
            for (int j = 0; j < 4; j++)
                acc[i][j] = __builtin_amdgcn_mfma_f32_16x16x32_bf16(af[i], bf8[j], acc[i][j], 0, 0, 0);
        __syncthreads();
    }

#pragma unroll
    for (int j = 0; j < 4; j++) {
        int n = n0 + RN + j * 16 + ln;
        float bb = bias[n];
#pragma unroll
        for (int i = 0; i < 4; i++) {
#pragma unroll
            for (int r = 0; r < 4; r++) {
                int m = m0 + RM + i * 16 + qd * 4 + r;
                Pj[(size_t)m * 1024 + n] = acc[i][j][r] + bb;
            }
        }
    }
}

// ---------------- flash attention: per (b,h), 128-row Q tiles ----------------
__global__ __launch_bounds__(256) void attn_kernel(const ushortT* __restrict__ Q,
        const ushortT* __restrict__ K, const ushortT* __restrict__ V,
        const float* __restrict__ mask, ushortT* __restrict__ ctx) {
    __shared__ ushortT Qs[128 * 64];    // 16 KB
    __shared__ ushortT PsKs[128 * 128]; // 32 KB: first 16KB doubles as K-tile [128][64]
    __shared__ ushortT Vt[64 * 128];    // 16 KB: V transposed [d][s]
    ushortT* Ks = PsKs;

    const int tid = threadIdx.x;
    const int lane = tid & 63;
    const int w = tid >> 6;
    const int qd = lane >> 4;
    const int ln = lane & 15;
    const int bh = blockIdx.y;
    const int b = bh >> 4;
    const int h = bh & 15;
    const int qb = blockIdx.x;

    const ushortT* Qg = Q + (size_t)(bh * 1024 + qb * 128) * 64;
    const ushortT* Kg = K + (size_t)bh * 1024 * 64;
    const ushortT* Vg = V + (size_t)bh * 1024 * 64;

#pragma unroll
    for (int it = 0; it < 4; ++it) {
        int c = it * 256 + tid;
        gload_lds16(Qg + (c >> 3) * 64 + (c & 7) * 8, Qs + c * 8);
    }

    float mst[2][4], lst[2][4];
    floatx4 accO[2][4];
#pragma unroll
    for (int i = 0; i < 2; i++)
#pragma unroll
        for (int r = 0; r < 4; r++) { mst[i][r] = -3.0e38f; lst[i][r] = 0.f; }
#pragma unroll
    for (int i = 0; i < 2; i++)
#pragma unroll
        for (int n = 0; n < 4; n++) accO[i][n] = (floatx4){0.f, 0.f, 0.f, 0.f};

    const float LOG2E = 1.4426950408889634f;

    for (int kt = 0; kt < 8; ++kt) {
        // stage K tile [128][64]
#pragma unroll
        for (int it = 0; it < 4; ++it) {
            int c = it * 256 + tid;
            gload_lds16(Kg + (kt * 128 + (c >> 3)) * 64 + (c & 7) * 8, Ks + c * 8);
        }
        // stage V transposed [64][128]
#pragma unroll
        for (int it = 0; it < 8; ++it) {
            int c = it * 256 + tid;       // 2048 chunks of 4 elements
            int s = c >> 4;
            int d0 = (c & 15) * 4;
            uint2 pk = *(const uint2*)(Vg + (kt * 128 + s) * 64 + d0);
            Vt[(d0 + 0) * 128 + s] = (ushortT)(pk.x & 0xffffu);
            Vt[(d0 + 1) * 128 + s] = (ushortT)(pk.x >> 16);
            Vt[(d0 + 2) * 128 + s] = (ushortT)(pk.y & 0xffffu);
            Vt[(d0 + 3) * 128 + s] = (ushortT)(pk.y >> 16);
        }
        __syncthreads();

        // S = Q K^T : wave strip 32 rows x 128 cols
        floatx4 sacc[2][8];
#pragma unroll
        for (int i = 0; i < 2; i++)
#pragma unroll
            for (int j = 0; j < 8; j++) sacc[i][j] = (floatx4){0.f, 0.f, 0.f, 0.f};
#pragma unroll
        for (int ks = 0; ks < 2; ++ks) {
            short8 aq[2], bk8[8];
#pragma unroll
            for (int i = 0; i < 2; i++)
                aq[i] = *(const short8*)&Qs[(w * 32 + i * 16 + ln) * 64 + ks * 32 + qd * 8];
#pragma unroll
            for (int j = 0; j < 8; j++)
                bk8[j] = *(const short8*)&Ks[(j * 16 + ln) * 64 + ks * 32 + qd * 8];
#pragma unroll
            for (int i = 0; i < 2; i++)
#pragma unroll
                for (int j = 0; j < 8; j++)
                    sacc[i][j] = __builtin_amdgcn_mfma_f32_16x16x32_bf16(aq[i], bk8[j], sacc[i][j], 0, 0, 0);
        }
        __syncthreads();  // all waves done reading Ks before P overwrites it

        // scale + mask + online softmax
        float mk8[8];
#pragma unroll
        for (int j = 0; j < 8; j++) mk8[j] = mask[b * 1024 + kt * 128 + j * 16 + ln];
        float rmax[2][4];
#pragma unroll
        for (int i = 0; i < 2; i++)
#pragma unroll
            for (int r = 0; r < 4; r++) rmax[i][r] = -3.0e38f;
#pragma unroll
        for (int i = 0; i < 2; i++)
#pragma unroll
            for (int j = 0; j < 8; j++)
#pragma unroll
                for (int r = 0; r < 4; r++) {
                    float v = sacc[i][j][r] * 0.125f + mk8[j];
                    sacc[i][j][r] = v;
                    rmax[i][r] = fmaxf(rmax[i][r], v);
                }
#pragma unroll
        for (int o = 1; o < 16; o <<= 1)
#pragma unroll
            for (int i = 0; i < 2; i++)
#pragma unroll
                for (int r = 0; r < 4; r++)
                    rmax[i][r] = fmaxf(rmax[i][r], __shfl_xor(rmax[i][r], o, 64));
        float alpha[2][4], rsum[2][4];
#pragma unroll
        for (int i = 0; i < 2; i++)
#pragma unroll
            for (int r = 0; r < 4; r++) {
                float mn = fmaxf(mst[i][r], rmax[i][r]);
                alpha[i][r] = exp2f((mst[i][r] - mn) * LOG2E);
                mst[i][r] = mn;
                rsum[i][r] = 0.f;
            }
#pragma unroll
        for (int i = 0; i < 2; i++)
#pragma unroll
            for (int j = 0; j < 8; j++)
#pragma unroll
                for (int r = 0; r < 4; r++) {
                    float p = exp2f((sacc[i][j][r] - mst[i][r]) * LOG2E);
                    sacc[i][j][r] = p;
                    rsum[i][r] += p;
                }
#pragma unroll
        for (int o = 1; o < 16; o <<= 1)
#pragma unroll
            for (int i = 0; i < 2; i++)
#pragma unroll
                for (int r = 0; r < 4; r++) rsum[i][r] += __shfl_xor(rsum[i][r], o, 64);
#pragma unroll
        for (int i = 0; i < 2; i++)
#pragma unroll
            for (int r = 0; r < 4; r++) lst[i][r] = lst[i][r] * alpha[i][r] + rsum[i][r];
#pragma unroll
        for (int i = 0; i < 2; i++)
#pragma unroll
            for (int n = 0; n < 4; n++)
#pragma unroll
                for (int r = 0; r < 4; r++) accO[i][n][r] *= alpha[i][r];

        // write P strip (bf16) into Ps [128][128]
#pragma unroll
        for (int i = 0; i < 2; i++)
#pragma unroll
            for (int j = 0; j < 8; j++)
#pragma unroll
                for (int r = 0; r < 4; r++)
                    PsKs[(w * 32 + i * 16 + qd * 4 + r) * 128 + j * 16 + ln] = f2bf(sacc[i][j][r]);
        __syncthreads();

        // O += P V
#pragma unroll
        for (int ks = 0; ks < 4; ++ks) {
            short8 ap[2], bv8[4];
#pragma unroll
            for (int i = 0; i < 2; i++)
                ap[i] = *(const short8*)&PsKs[(w * 32 + i * 16 + ln) * 128 + ks * 32 + qd * 8];
#pragma unroll
            for (int n = 0; n < 4; n++)
                bv8[n] = *(const short8*)&Vt[(n * 16 + ln) * 128 + ks * 32 + qd * 8];
#pragma unroll
            for (int i = 0; i < 2; i++)
#pragma unroll
                for (int n = 0; n < 4; n++)
                    accO[i][n] = __builtin_amdgcn_mfma_f32_16x16x32_bf16(ap[i], bv8[n], accO[i][n], 0, 0, 0);
        }
        __syncthreads();
    }

    // epilogue: ctx[b, s, h*64+d] bf16
#pragma unroll
    for (int i = 0; i < 2; i++)
#pragma unroll
        for (int n = 0; n < 4; n++)
#pragma unroll
            for (int r = 0; r < 4; r++) {
                int s = qb * 128 + w * 32 + i * 16 + qd * 4 + r;
                int d = n * 16 + ln;
                float v = accO[i][n][r] / lst[i][r];
                ctx[(size_t)(b * 1024 + s) * 1024 + h * 64 + d] = f2bf(v);
            }
}

// ---------------- residual + LayerNorm ----------------
__global__ __launch_bounds__(256) void ln_kernel(const float* __restrict__ Pj, const float* __restrict__ X,
        const float* __restrict__ gamma, const float* __restrict__ beta, float* __restrict__ out) {
    __shared__ float red[8];
    int row = blockIdx.x;
    int t = threadIdx.x;
    const float4 p4 = ((const float4*)(Pj + (size_t)row * 1024))[t];
    const float4 x4 = ((const float4*)(X + (size_t)row * 1024))[t];
    float r0 = p4.x + x4.x, r1 = p4.y + x4.y, r2 = p4.z + x4.z, r3 = p4.w + x4.w;
    float s = r0 + r1 + r2 + r3;
    float ss = r0 * r0 + r1 * r1 + r2 * r2 + r3 * r3;
#pragma unroll
    for (int o = 1; o < 64; o <<= 1) { s += __shfl_xor(s, o, 64); ss += __shfl_xor(ss, o, 64); }
    int w = t >> 6;
    if ((t & 63) == 0) { red[w] = s; red[4 + w] = ss; }
    __syncthreads();
    s = red[0] + red[1] + red[2] + red[3];
    ss = red[4] + red[5] + red[6] + red[7];
    float mu = s * (1.f / 1024.f);
    float var = ss * (1.f / 1024.f) - mu * mu;
    float inv = rsqrtf(var + 1e-12f);
    const float4 g4 = ((const float4*)gamma)[t];
    const float4 b4 = ((const float4*)beta)[t];
    float4 o4;
    o4.x = (r0 - mu) * inv * g4.x + b4.x;
    o4.y = (r1 - mu) * inv * g4.y + b4.y;
    o4.z = (r2 - mu) * inv * g4.z + b4.z;
    o4.w = (r3 - mu) * inv * g4.w + b4.w;
    ((float4*)(out + (size_t)row * 1024))[t] = o4;
}

extern "C" void kernel_launch(void* const* d_in, const int* in_sizes, int n_in,
                              void* d_out, int out_size, void* d_ws, size_t ws_size,
                              hipStream_t stream) {
    const float* x     = (const float*)d_in[0];
    const float* mask  = (const float*)d_in[1];
    const float* Wq    = (const float*)d_in[2];
    const float* bq    = (const float*)d_in[3];
    const float* Wk    = (const float*)d_in[4];
    const float* bk    = (const float*)d_in[5];
    const float* Wv    = (const float*)d_in[6];
    const float* bv    = (const float*)d_in[7];
    const float* Wo    = (const float*)d_in[8];
    const float* bo    = (const float*)d_in[9];
    const float* gamma = (const float*)d_in[10];
    const float* beta  = (const float*)d_in[11];
    float* out = (float*)d_out;

    char* ws = (char*)d_ws;
    // layout (MB): [0,16) Xb (later reused as ctx) | [16,24) W bf16 x4 |
    // [24,40) Qb | [40,56) Kb | [56,72) Vb | Pj fp32 aliases [24,56)
    ushortT* Xb  = (ushortT*)(ws);
    ushortT* Wqb = (ushortT*)(ws + (16u << 20));
    ushortT* Wkb = (ushortT*)(ws + (18u << 20));
    ushortT* Wvb = (ushortT*)(ws + (20u << 20));
    ushortT* Wob = (ushortT*)(ws + (22u << 20));
    ushortT* Qb  = (ushortT*)(ws + (24u << 20));
    ushortT* Kb  = (ushortT*)(ws + (40u << 20));
    ushortT* Vb  = (ushortT*)(ws + (56u << 20));
    ushortT* Cb  = (ushortT*)(ws);               // ctx reuses Xb (dead after qkv_gemm)
    float*   Pj  = (float*)(ws + (24u << 20));   // fp32 proj reuses Q/K (dead after attn)

    cvt_x<<<8192, 256, 0, stream>>>(x, Xb, 2097152);
    cvt_w<<<dim3(1024, 4), 256, 0, stream>>>(Wq, Wk, Wv, Wo, Wqb, Wkb, Wvb, Wob, 262144);
    qkv_gemm<<<dim3(8, 64, 3), 256, 0, stream>>>(Xb, Wqb, Wkb, Wvb, bq, bk, bv, Qb, Kb, Vb);
    attn_kernel<<<dim3(8, 128), 256, 0, stream>>>(Qb, Kb, Vb, mask, Cb);
    oproj_gemm<<<dim3(8, 64), 256, 0, stream>>>(Cb, Wob, bo, Pj);
    ln_kernel<<<8192, 256, 0, stream>>>(Pj, x, gamma, beta, out);
}

// Round 2
// 368.524 us; speedup vs baseline: 1.1687x; 1.1687x over previous
//
#include <hip/hip_runtime.h>

#define NHh 16

typedef unsigned short ushortT;
typedef __attribute__((ext_vector_type(8))) short short8;
typedef __attribute__((ext_vector_type(4))) float floatx4;
typedef __attribute__((ext_vector_type(4))) unsigned short ushort4v;

__device__ __forceinline__ ushortT f2bf(float x) {
    union { float f; unsigned int u; } cv; cv.f = x;
    unsigned int u = cv.u;
    unsigned int r = u + 0x7fffu + ((u >> 16) & 1u);
    return (ushortT)(r >> 16);
}

__device__ __forceinline__ void gload_lds16(const ushortT* g, ushortT* l) {
    __builtin_amdgcn_global_load_lds(
        (const __attribute__((address_space(1))) void*)g,
        (__attribute__((address_space(3))) void*)l, 16, 0, 0);
}

// ---------------- fp32 -> bf16 converters ----------------
__global__ __launch_bounds__(256) void cvt_x(const float* __restrict__ in,
                                             ushortT* __restrict__ out, int n4) {
    int i = blockIdx.x * 256 + threadIdx.x;
    if (i >= n4) return;
    float4 f = ((const float4*)in)[i];
    uint2 o;
    o.x = (unsigned)f2bf(f.x) | ((unsigned)f2bf(f.y) << 16);
    o.y = (unsigned)f2bf(f.z) | ((unsigned)f2bf(f.w) << 16);
    ((uint2*)out)[i] = o;
}

__global__ __launch_bounds__(256) void cvt_w(const float* __restrict__ W0, const float* __restrict__ W1,
                                             const float* __restrict__ W2, const float* __restrict__ W3,
                                             ushortT* __restrict__ o0, ushortT* __restrict__ o1,
                                             ushortT* __restrict__ o2, ushortT* __restrict__ o3, int n4) {
    int z = blockIdx.y;
    const float* in = (z == 0) ? W0 : (z == 1) ? W1 : (z == 2) ? W2 : W3;
    ushortT* out = (z == 0) ? o0 : (z == 1) ? o1 : (z == 2) ? o2 : o3;
    int i = blockIdx.x * 256 + threadIdx.x;
    if (i >= n4) return;
    float4 f = ((const float4*)in)[i];
    uint2 o;
    o.x = (unsigned)f2bf(f.x) | ((unsigned)f2bf(f.y) << 16);
    o.y = (unsigned)f2bf(f.z) | ((unsigned)f2bf(f.w) << 16);
    ((uint2*)out)[i] = o;
}

// ---------------- QKV GEMM ----------------
// z=0/1 (Q,K): out[m=token, n=dim], stored [bh][s][d].
// z=2  (V):    operands swapped -> C^T emitted directly, stored V^T [bh][d][s].
__global__ __launch_bounds__(256) void qkv_gemm(const ushortT* __restrict__ X,
        const ushortT* __restrict__ W0, const ushortT* __restrict__ W1, const ushortT* __restrict__ W2,
        const float* __restrict__ b0, const float* __restrict__ b1, const float* __restrict__ b2,
        ushortT* __restrict__ Qo, ushortT* __restrict__ Ko, ushortT* __restrict__ Vo) {
    __shared__ ushortT As[128 * 32];
    __shared__ ushortT Bs[128 * 32];
    const int tid = threadIdx.x;
    const int lane = tid & 63;
    const int w = tid >> 6;
    const int qd = lane >> 4;
    const int ln = lane & 15;
    const int z = blockIdx.z;
    const ushortT* Wt = (z == 0) ? W0 : (z == 1) ? W1 : W2;
    const float* bias = (z == 0) ? b0 : (z == 1) ? b1 : b2;
    const int RM = (w >> 1) * 64;
    const int RN = (w & 1) * 64;

    const ushortT* Ap;
    const ushortT* Bp;
    int arow0, brow0;
    if (z == 2) { Ap = Wt; arow0 = blockIdx.x * 128; Bp = X;  brow0 = blockIdx.y * 128; }
    else        { Ap = X;  arow0 = blockIdx.y * 128; Bp = Wt; brow0 = blockIdx.x * 128; }

    floatx4 acc[4][4];
#pragma unroll
    for (int i = 0; i < 4; i++)
#pragma unroll
        for (int j = 0; j < 4; j++) acc[i][j] = (floatx4){0.f, 0.f, 0.f, 0.f};

    const int c0 = tid, c1 = tid + 256;
    for (int k0 = 0; k0 < 1024; k0 += 32) {
        gload_lds16(Ap + (size_t)(arow0 + (c0 >> 2)) * 1024 + k0 + (c0 & 3) * 8, As + c0 * 8);
        gload_lds16(Ap + (size_t)(arow0 + (c1 >> 2)) * 1024 + k0 + (c1 & 3) * 8, As + c1 * 8);
        gload_lds16(Bp + (size_t)(brow0 + (c0 >> 2)) * 1024 + k0 + (c0 & 3) * 8, Bs + c0 * 8);
        gload_lds16(Bp + (size_t)(brow0 + (c1 >> 2)) * 1024 + k0 + (c1 & 3) * 8, Bs + c1 * 8);
        __syncthreads();
        short8 af[4], bf8[4];
#pragma unroll
        for (int i = 0; i < 4; i++) af[i] = *(const short8*)&As[(RM + i * 16 + ln) * 32 + qd * 8];
#pragma unroll
        for (int j = 0; j < 4; j++) bf8[j] = *(const short8*)&Bs[(RN + j * 16 + ln) * 32 + qd * 8];
#pragma unroll
        for (int i = 0; i < 4; i++)
#pragma unroll
            for (int j = 0; j < 4; j++)
                acc[i][j] = __builtin_amdgcn_mfma_f32_16x16x32_bf16(af[i], bf8[j], acc[i][j], 0, 0, 0);
        __syncthreads();
    }

    if (z == 2) {
        // acc[i][j][r]: row a = dim = arow0+RM+i*16+qd*4+r ; col = token = brow0+RN+j*16+ln
        floatx4 bias4[4];
#pragma unroll
        for (int i = 0; i < 4; i++) bias4[i] = *(const floatx4*)(bias + arow0 + RM + i * 16 + qd * 4);
#pragma unroll
        for (int j = 0; j < 4; j++) {
            int m = brow0 + RN + j * 16 + ln;   // token
            int bb = m >> 10, s = m & 1023;
#pragma unroll
            for (int i = 0; i < 4; i++) {
#pragma unroll
                for (int r = 0; r < 4; r++) {
                    int a = arow0 + RM + i * 16 + qd * 4 + r;  // dim
                    int hh = a >> 6, dd = a & 63;
                    float v = acc[i][j][r] + bias4[i][r];
                    Vo[((size_t)(bb * NHh + hh) * 64 + dd) * 1024 + s] = f2bf(v);
                }
            }
        }
    } else {
        ushortT* Out = (z == 0) ? Qo : Ko;
#pragma unroll
        for (int j = 0; j < 4; j++) {
            int n = brow0 + RN + j * 16 + ln;   // dim
            float bb = bias[n];
            int h = n >> 6, d = n & 63;
#pragma unroll
            for (int i = 0; i < 4; i++) {
#pragma unroll
                for (int r = 0; r < 4; r++) {
                    int m = arow0 + RM + i * 16 + qd * 4 + r;  // token
                    int b = m >> 10, s = m & 1023;
                    float v = acc[i][j][r] + bb;
                    Out[(size_t)((b * NHh + h) * 1024 + s) * 64 + d] = f2bf(v);
                }
            }
        }
    }
}

// ---------------- out-proj GEMM (fp32 out) ----------------
__global__ __launch_bounds__(256) void oproj_gemm(const ushortT* __restrict__ A,
        const ushortT* __restrict__ Wt, const float* __restrict__ bias, float* __restrict__ Pj) {
    __shared__ ushortT As[128 * 32];
    __shared__ ushortT Bs[128 * 32];
    const int tid = threadIdx.x;
    const int lane = tid & 63;
    const int w = tid >> 6;
    const int qd = lane >> 4;
    const int ln = lane & 15;
    const int m0 = blockIdx.y * 128;
    const int n0 = blockIdx.x * 128;
    const int RM = (w >> 1) * 64;
    const int RN = (w & 1) * 64;

    floatx4 acc[4][4];
#pragma unroll
    for (int i = 0; i < 4; i++)
#pragma unroll
        for (int j = 0; j < 4; j++) acc[i][j] = (floatx4){0.f, 0.f, 0.f, 0.f};

    const int c0 = tid, c1 = tid + 256;
    for (int k0 = 0; k0 < 1024; k0 += 32) {
        gload_lds16(A + (size_t)(m0 + (c0 >> 2)) * 1024 + k0 + (c0 & 3) * 8, As + c0 * 8);
        gload_lds16(A + (size_t)(m0 + (c1 >> 2)) * 1024 + k0 + (c1 & 3) * 8, As + c1 * 8);
        gload_lds16(Wt + (size_t)(n0 + (c0 >> 2)) * 1024 + k0 + (c0 & 3) * 8, Bs + c0 * 8);
        gload_lds16(Wt + (size_t)(n0 + (c1 >> 2)) * 1024 + k0 + (c1 & 3) * 8, Bs + c1 * 8);
        __syncthreads();
        short8 af[4], bf8[4];
#pragma unroll
        for (int i = 0; i < 4; i++) af[i] = *(const short8*)&As[(RM + i * 16 + ln) * 32 + qd * 8];
#pragma unroll
        for (int j = 0; j < 4; j++) bf8[j] = *(const short8*)&Bs[(RN + j * 16 + ln) * 32 + qd * 8];
#pragma unroll
        for (int i = 0; i < 4; i++)
#pragma unroll
            for (int j = 0; j < 4; j++)
                acc[i][j] = __builtin_amdgcn_mfma_f32_16x16x32_bf16(af[i], bf8[j], acc[i][j], 0, 0, 0);
        __syncthreads();
    }

#pragma unroll
    for (int j = 0; j < 4; j++) {
        int n = n0 + RN + j * 16 + ln;
        float bb = bias[n];
#pragma unroll
        for (int i = 0; i < 4; i++) {
#pragma unroll
            for (int r = 0; r < 4; r++) {
                int m = m0 + RM + i * 16 + qd * 4 + r;
                Pj[(size_t)m * 1024 + n] = acc[i][j][r] + bb;
            }
        }
    }
}

// ---------------- flash attention, S^T formulation ----------------
// Per block: 128 q rows, one (b,h). Waves own 32 q each.
// S^T = K·Q^T  (A=K from global, B=Q register-resident) -> C-frag has s contiguous
// P written as packed b64 in A-layout; PV: A=P (LDS, per-wave), B=V^T (LDS, swizzled).
__global__ __launch_bounds__(256, 3) void attn_kernel(const ushortT* __restrict__ Q,
        const ushortT* __restrict__ K, const ushortT* __restrict__ Vg_t,
        const float* __restrict__ mask, ushortT* __restrict__ ctx) {
    __shared__ __align__(16) ushortT Vt[64 * 128];      // 16 KB, chunk-swizzled: chunk c of row d at slot c^(d&15)
    __shared__ __align__(16) ushortT Ps[4][32 * 72];    // 18 KB, per-wave P half-tile [32 q][64 s + pad]

    const int tid = threadIdx.x;
    const int lane = tid & 63;
    const int w = tid >> 6;
    const int qd = lane >> 4;
    const int ln = lane & 15;
    const int bh = blockIdx.y;
    const int b = bh >> 4;
    const int h = bh & 15;
    const int qb = blockIdx.x;

    const ushortT* Qg = Q + (size_t)bh * 65536;
    const ushortT* Kg = K + (size_t)bh * 65536;
    const ushortT* Vg = Vg_t + (size_t)bh * 65536;
    const float* mrow = mask + b * 1024;
    const float LOG2E = 1.4426950408889634f;

    // resident Q B-fragments: n=q = qb*128 + w*32 + nj*16 + ln, k=d
    short8 qf[2][2];
#pragma unroll
    for (int nj = 0; nj < 2; nj++)
#pragma unroll
        for (int ks = 0; ks < 2; ks++)
            qf[nj][ks] = *(const short8*)(Qg + (size_t)(qb * 128 + w * 32 + nj * 16 + ln) * 64 + ks * 32 + qd * 8);

    float mst[2] = {-3.0e38f, -3.0e38f};
    float lst[2] = {0.f, 0.f};
    floatx4 accO[2][4];
#pragma unroll
    for (int i = 0; i < 2; i++)
#pragma unroll
        for (int j = 0; j < 4; j++) accO[i][j] = (floatx4){0.f, 0.f, 0.f, 0.f};

    for (int kt = 0; kt < 8; ++kt) {
        __syncthreads();   // previous PV done reading Vt
        // stage V^T tile [64 d][128 s] via async gload, chunk-swizzled
#pragma unroll
        for (int ii = 0; ii < 4; ii++) {
            int i = w * 4 + ii;
            int d = i * 4 + (lane >> 4);
            int c = (lane & 15) ^ (d & 15);
            gload_lds16(Vg + (size_t)d * 1024 + kt * 128 + c * 8, Vt + i * 512 + lane * 8);
        }

#pragma unroll
        for (int h2 = 0; h2 < 2; h2++) {
            // ---- S^T = K Q^T over 64 s rows ----
            floatx4 sv[4][2];
#pragma unroll
            for (int mi = 0; mi < 4; mi++)
#pragma unroll
                for (int nj = 0; nj < 2; nj++) sv[mi][nj] = (floatx4){0.f, 0.f, 0.f, 0.f};
#pragma unroll
            for (int ks = 0; ks < 2; ks++) {
                short8 af[4];
#pragma unroll
                for (int mi = 0; mi < 4; mi++)
                    af[mi] = *(const short8*)(Kg + (size_t)(kt * 128 + h2 * 64 + mi * 16 + ln) * 64 + ks * 32 + qd * 8);
#pragma unroll
                for (int mi = 0; mi < 4; mi++)
#pragma unroll
                    for (int nj = 0; nj < 2; nj++)
                        sv[mi][nj] = __builtin_amdgcn_mfma_f32_16x16x32_bf16(af[mi], qf[nj][ks], sv[mi][nj], 0, 0, 0);
            }
            // scale + mask (broadcast float4 loads; all ln lanes share address)
#pragma unroll
            for (int mi = 0; mi < 4; mi++) {
                floatx4 m4 = *(const floatx4*)(mrow + kt * 128 + h2 * 64 + mi * 16 + qd * 4);
#pragma unroll
                for (int nj = 0; nj < 2; nj++)
#pragma unroll
                    for (int r = 0; r < 4; r++)
                        sv[mi][nj][r] = sv[mi][nj][r] * 0.125f + m4[r];
            }
            // online softmax per q (= ln domain); s spread over (mi, r, qd)
            float alpha[2], rsum[2];
#pragma unroll
            for (int nj = 0; nj < 2; nj++) {
                float mx = -3.0e38f;
#pragma unroll
                for (int mi = 0; mi < 4; mi++)
#pragma unroll
                    for (int r = 0; r < 4; r++) mx = fmaxf(mx, sv[mi][nj][r]);
                mx = fmaxf(mx, __shfl_xor(mx, 16, 64));
                mx = fmaxf(mx, __shfl_xor(mx, 32, 64));
                float mn = fmaxf(mst[nj], mx);
                alpha[nj] = __builtin_amdgcn_exp2f((mst[nj] - mn) * LOG2E);
                mst[nj] = mn;
                float rs = 0.f;
#pragma unroll
                for (int mi = 0; mi < 4; mi++)
#pragma unroll
                    for (int r = 0; r < 4; r++) {
                        float p = __builtin_amdgcn_exp2f((sv[mi][nj][r] - mn) * LOG2E);
                        sv[mi][nj][r] = p;
                        rs += p;
                    }
                rs += __shfl_xor(rs, 16, 64);
                rs += __shfl_xor(rs, 32, 64);
                rsum[nj] = rs;
                lst[nj] = lst[nj] * alpha[nj] + rs;
            }
            // rescale accO: alpha lives in ln-domain, accO rows in qd-domain -> lane transpose
#pragma unroll
            for (int i = 0; i < 2; i++) {
#pragma unroll
                for (int r = 0; r < 4; r++) {
                    float a = __shfl(alpha[i], qd * 4 + r, 64);
#pragma unroll
                    for (int j = 0; j < 4; j++) accO[i][j][r] *= a;
                }
            }
            // write P: packed b64, A-layout [q][s] (per-wave region, no barrier needed)
#pragma unroll
            for (int nj = 0; nj < 2; nj++)
#pragma unroll
                for (int mi = 0; mi < 4; mi++) {
                    ushort4v pk;
#pragma unroll
                    for (int r = 0; r < 4; r++) pk[r] = f2bf(sv[mi][nj][r]);
                    *(ushort4v*)&Ps[w][(nj * 16 + ln) * 72 + mi * 16 + qd * 4] = pk;
                }

            if (h2 == 0) __syncthreads();   // Vt staged (drains vmcnt)

            // ---- O += P V over this 64-s half ----
#pragma unroll
            for (int ks2 = 0; ks2 < 2; ks2++) {
                short8 ap[2], bv[4];
#pragma unroll
                for (int i = 0; i < 2; i++)
                    ap[i] = *(const short8*)&Ps[w][(i * 16 + ln) * 72 + ks2 * 32 + qd * 8];
#pragma unroll
                for (int j = 0; j < 4; j++) {
                    int d = j * 16 + ln;
                    int slot = (h2 * 8 + ks2 * 4 + qd) ^ ln;
                    bv[j] = *(const short8*)&Vt[d * 128 + slot * 8];
                }
#pragma unroll
                for (int i = 0; i < 2; i++)
#pragma unroll
                    for (int j = 0; j < 4; j++)
                        accO[i][j] = __builtin_amdgcn_mfma_f32_16x16x32_bf16(ap[i], bv[j], accO[i][j], 0, 0, 0);
            }
        }
    }

    // epilogue: divide by l (lane transpose) and store ctx [b][s=q][h*64+d]
#pragma unroll
    for (int i = 0; i < 2; i++) {
#pragma unroll
        for (int r = 0; r < 4; r++) {
            float l = __shfl(lst[i], qd * 4 + r, 64);
            float linv = 1.f / l;
            int q = qb * 128 + w * 32 + i * 16 + qd * 4 + r;
#pragma unroll
            for (int j = 0; j < 4; j++) {
                int d = j * 16 + ln;
                ctx[((size_t)(b * 1024 + q)) * 1024 + h * 64 + d] = f2bf(accO[i][j][r] * linv);
            }
        }
    }
}

// ---------------- residual + LayerNorm ----------------
__global__ __launch_bounds__(256) void ln_kernel(const float* __restrict__ Pj, const float* __restrict__ X,
        const float* __restrict__ gamma, const float* __restrict__ beta, float* __restrict__ out) {
    __shared__ float red[8];
    int row = blockIdx.x;
    int t = threadIdx.x;
    const float4 p4 = ((const float4*)(Pj + (size_t)row * 1024))[t];
    const float4 x4 = ((const float4*)(X + (size_t)row * 1024))[t];
    float r0 = p4.x + x4.x, r1 = p4.y + x4.y, r2 = p4.z + x4.z, r3 = p4.w + x4.w;
    float s = r0 + r1 + r2 + r3;
    float ss = r0 * r0 + r1 * r1 + r2 * r2 + r3 * r3;
#pragma unroll
    for (int o = 1; o < 64; o <<= 1) { s += __shfl_xor(s, o, 64); ss += __shfl_xor(ss, o, 64); }
    int w = t >> 6;
    if ((t & 63) == 0) { red[w] = s; red[4 + w] = ss; }
    __syncthreads();
    s = red[0] + red[1] + red[2] + red[3];
    ss = red[4] + red[5] + red[6] + red[7];
    float mu = s * (1.f / 1024.f);
    float var = ss * (1.f / 1024.f) - mu * mu;
    float inv = rsqrtf(var + 1e-12f);
    const float4 g4 = ((const float4*)gamma)[t];
    const float4 b4 = ((const float4*)beta)[t];
    float4 o4;
    o4.x = (r0 - mu) * inv * g4.x + b4.x;
    o4.y = (r1 - mu) * inv * g4.y + b4.y;
    o4.z = (r2 - mu) * inv * g4.z + b4.z;
    o4.w = (r3 - mu) * inv * g4.w + b4.w;
    ((float4*)(out + (size_t)row * 1024))[t] = o4;
}

extern "C" void kernel_launch(void* const* d_in, const int* in_sizes, int n_in,
                              void* d_out, int out_size, void* d_ws, size_t ws_size,
                              hipStream_t stream) {
    const float* x     = (const float*)d_in[0];
    const float* mask  = (const float*)d_in[1];
    const float* Wq    = (const float*)d_in[2];
    const float* bq    = (const float*)d_in[3];
    const float* Wk    = (const float*)d_in[4];
    const float* bk    = (const float*)d_in[5];
    const float* Wv    = (const float*)d_in[6];
    const float* bv    = (const float*)d_in[7];
    const float* Wo    = (const float*)d_in[8];
    const float* bo    = (const float*)d_in[9];
    const float* gamma = (const float*)d_in[10];
    const float* beta  = (const float*)d_in[11];
    float* out = (float*)d_out;

    char* ws = (char*)d_ws;
    ushortT* Xb  = (ushortT*)(ws);
    ushortT* Wqb = (ushortT*)(ws + (16u << 20));
    ushortT* Wkb = (ushortT*)(ws + (18u << 20));
    ushortT* Wvb = (ushortT*)(ws + (20u << 20));
    ushortT* Wob = (ushortT*)(ws + (22u << 20));
    ushortT* Qb  = (ushortT*)(ws + (24u << 20));
    ushortT* Kb  = (ushortT*)(ws + (40u << 20));
    ushortT* Vb  = (ushortT*)(ws + (56u << 20));  // V^T [bh][d][s]
    ushortT* Cb  = (ushortT*)(ws);                // ctx reuses Xb
    float*   Pj  = (float*)(ws + (24u << 20));    // fp32 proj reuses Q/K

    cvt_x<<<8192, 256, 0, stream>>>(x, Xb, 2097152);
    cvt_w<<<dim3(1024, 4), 256, 0, stream>>>(Wq, Wk, Wv, Wo, Wqb, Wkb, Wvb, Wob, 262144);
    qkv_gemm<<<dim3(8, 64, 3), 256, 0, stream>>>(Xb, Wqb, Wkb, Wvb, bq, bk, bv, Qb, Kb, Vb);
    attn_kernel<<<dim3(8, 128), 256, 0, stream>>>(Qb, Kb, Vb, mask, Cb);
    oproj_gemm<<<dim3(8, 64), 256, 0, stream>>>(Cb, Wob, bo, Pj);
    ln_kernel<<<8192, 256, 0, stream>>>(Pj, x, gamma, beta, out);
}